// Round 4
// baseline (154.854 us; speedup 1.0000x reference)
//
#include <hip/hip_runtime.h>

// Bahdanau attention, fused. query [8][400][256], y [8][400][256],
// Wq_w [128][256], Wq_b [128], Wy_w [128][256], Wy_b [128], v_w [1][128],
// v_b (dropped: softmax shift-invariant), n_wins_y [8] i32. out [8][400][256] f32.
// score = sum_a v_a*tanh(qp+yp) ~ sum_a (-2 v_a)*sigmoid-like (const dropped).
// qp/yp prescaled by 2*log2(e) so exp2(qp'+yp') = e^{2x}. One rcp per 4 elems:
// r_i = 1/(e_i+1) via R = rcp(a0a1a2a3), r0 = a1*(a2a3*R), etc.
//
// R3: __launch_bounds__(256,4) — R2's compiler chose 64 VGPRs (32-wave target)
// and spilled the pf[8] prefetch array to scratch: WRITE_SIZE 3.2MB -> 288MB.
// Grid is only 12.5 waves/CU, so cap occupancy at 16 waves/CU and keep the
// prefetch in registers.

#define LOG2E 1.4426950408889634f
#define TANH_SCALE 2.8853900817779268f  // 2*log2(e)

constexpr int TQn = 400, TYn = 400, AD = 128, DD = 256;
constexpr int QT = 4;              // queries per fused block (1 wave each)
constexpr int QBLOCKS = TQn / QT;  // 100
constexpr int YT = 64;             // score tile rows
constexpr int AT = 32;             // apply tile rows
constexpr int SSTR = 65;           // score LDS row stride in float4 (transposed layout)

// ---------------- projection: qp' = (query@WqT + bq)*S ; yp' likewise ----------
__global__ __launch_bounds__(128, 4) void proj_kernel(
    const float* __restrict__ qin, const float* __restrict__ yin,
    const float* __restrict__ Wq, const float* __restrict__ bq,
    const float* __restrict__ Wy, const float* __restrict__ by,
    float* __restrict__ qp, float* __restrict__ yp)
{
    // 800 blocks: [0,400) -> q rows, [400,800) -> y rows. 8 rows/block, thread=a.
    int blk = blockIdx.x;
    bool is_q = blk < 400;
    int row0 = (is_q ? blk : blk - 400) * 8;
    const float* in   = (is_q ? qin : yin) + (size_t)row0 * DD;
    const float* W    = is_q ? Wq : Wy;
    const float* bias = is_q ? bq : by;
    float* outp = (is_q ? qp : yp) + (size_t)row0 * AD;

    __shared__ float lin[8 * DD];
    {
        const float4* in4 = reinterpret_cast<const float4*>(in);
        float4* l4s = reinterpret_cast<float4*>(lin);
        for (int j = threadIdx.x; j < 8 * DD / 4; j += 128) l4s[j] = in4[j];
    }
    __syncthreads();

    int a = threadIdx.x;  // 0..127
    float acc[8] = {0.f,0.f,0.f,0.f,0.f,0.f,0.f,0.f};
    const float4* w4p = reinterpret_cast<const float4*>(W + (size_t)a * DD);
    const float4* l4 = reinterpret_cast<const float4*>(lin);
    #pragma unroll 4
    for (int d4 = 0; d4 < DD / 4; ++d4) {
        float4 w4 = w4p[d4];
        #pragma unroll
        for (int r = 0; r < 8; ++r) {
            float4 v = l4[r * (DD/4) + d4];  // broadcast
            acc[r] = fmaf(w4.x, v.x, acc[r]);
            acc[r] = fmaf(w4.y, v.y, acc[r]);
            acc[r] = fmaf(w4.z, v.z, acc[r]);
            acc[r] = fmaf(w4.w, v.w, acc[r]);
        }
    }
    float bb = bias[a];
    #pragma unroll
    for (int r = 0; r < 8; ++r)
        outp[(size_t)r * AD + a] = (acc[r] + bb) * TANH_SCALE;
}

// ---------------- fused scores -> masked softmax -> att @ y --------------------
__global__ __launch_bounds__(256, 4) void fused_kernel(
    const float* __restrict__ y,    // [B][TY][DD]
    const float* __restrict__ qp,   // [B*TQ][AD] prescaled
    const float* __restrict__ yp,   // [B*TY][AD] prescaled
    const float* __restrict__ vw,   // [AD]
    const int*  __restrict__ nwins, // [B]
    float* __restrict__ out)        // [B][TQ][DD]
{
    __shared__ float4 s_qp4[QT * 32];       // 2 KB
    __shared__ float4 s_v4[32];             // 0.5 KB (holds -2*v)
    __shared__ float4 s_buf4[32 * SSTR];    // 33.3 KB: score yp^T tile / apply y tile

    const int b  = blockIdx.x / QBLOCKS;
    const int q0 = (blockIdx.x % QBLOCKS) * QT;
    const int tid = threadIdx.x;
    const int wave = tid >> 6;   // local query
    const int lane = tid & 63;
    const int n = nwins[b];
    const float NEG_INF = -__builtin_inff();

    const float4* ypb = reinterpret_cast<const float4*>(yp);  // absolute rows [3200][32]f4
    const float4* yb  = reinterpret_cast<const float4*>(y);   // absolute rows [3200][64]f4
    const int prow = tid >> 5;   // 0..7
    const int pcol = tid & 31;   // a4 col

    float4 pf[8];
    // prefetch score tile 0 (rows 0..63 valid: n >= 200)
    #pragma unroll
    for (int k = 0; k < 8; ++k)
        pf[k] = ypb[(size_t)(b * TYn + k * 8 + prow) * 32 + pcol];

    // stage qp tile + (-2*v); visible after first loop barrier
    if (tid < QT * 32) {
        s_qp4[tid] = reinterpret_cast<const float4*>(qp + (size_t)(b * TQn + q0) * AD)[tid];
    } else if (tid < QT * 32 + 32) {
        float4 v = reinterpret_cast<const float4*>(vw)[tid - QT * 32];
        s_v4[tid - QT * 32] = make_float4(-2.f * v.x, -2.f * v.y, -2.f * v.z, -2.f * v.w);
    }

    float sc[7];
    #pragma unroll
    for (int j = 0; j < 7; ++j) sc[j] = NEG_INF;

    // ---- score phase: tiles of 64 t; lane <-> t, wave <-> q; early exit at n ----
    const int ntile = (n + YT - 1) >> 6;  // 4..7
    for (int i = 0; i < ntile; ++i) {
        __syncthreads();  // all waves done reading s_buf4 (and covers qp/v staging)
        #pragma unroll
        for (int k = 0; k < 8; ++k)
            s_buf4[pcol * SSTR + (k * 8 + prow)] = pf[k];  // transposed store
        if (i + 1 < ntile) {
            const int t0n = (i + 1) * YT;
            #pragma unroll
            for (int k = 0; k < 8; ++k) {
                int absrow = min(b * TYn + t0n + k * 8 + prow, 8 * TYn - 1);
                pf[k] = ypb[(size_t)absrow * 32 + pcol];  // overlaps compute below
            }
        }
        __syncthreads();
        float ac0 = 0.f, ac1 = 0.f, ac2 = 0.f, ac3 = 0.f;
        const float4* qrow = s_qp4 + wave * 32;
        #pragma unroll 8
        for (int a4 = 0; a4 < 32; ++a4) {
            float4 yv = s_buf4[a4 * SSTR + lane];  // contiguous 64-lane sweep
            float4 qv = qrow[a4];                  // wave-uniform broadcast
            float4 vv = s_v4[a4];                  // broadcast (-2v)
            float e0 = __builtin_amdgcn_exp2f(qv.x + yv.x);
            float e1 = __builtin_amdgcn_exp2f(qv.y + yv.y);
            float e2 = __builtin_amdgcn_exp2f(qv.z + yv.z);
            float e3 = __builtin_amdgcn_exp2f(qv.w + yv.w);
            float a0 = e0 + 1.f, a1 = e1 + 1.f, a2 = e2 + 1.f, a3 = e3 + 1.f;
            float p01 = a0 * a1, p23 = a2 * a3;
            float R = __builtin_amdgcn_rcpf(p01 * p23);
            float u = p23 * R, v = p01 * R;        // u = 1/p01, v = 1/p23
            ac0 = fmaf(vv.x, a1 * u, ac0);
            ac1 = fmaf(vv.y, a0 * u, ac1);
            ac2 = fmaf(vv.z, a3 * v, ac2);
            ac3 = fmaf(vv.w, a2 * v, ac3);
        }
        if (i * YT + lane < TYn)  // last tile may have lanes reading clamped rows
            sc[i] = (ac0 + ac1) + (ac2 + ac3);
    }

    // prefetch apply tile 0 (overlaps softmax); row = k*4 + wave, col = lane
    #pragma unroll
    for (int k = 0; k < 8; ++k) {
        int absrow = min(b * TYn + k * 4 + wave, 8 * TYn - 1);
        pf[k] = yb[(size_t)absrow * 64 + lane];
    }

    // ---- mask + softmax over t (full 64-lane wave per q) ----
    #pragma unroll
    for (int j = 0; j < 7; ++j) {
        int t = j * YT + lane;
        if (t >= n) sc[j] = NEG_INF;
    }
    float m = sc[0];
    #pragma unroll
    for (int j = 1; j < 7; ++j) m = fmaxf(m, sc[j]);
    #pragma unroll
    for (int off = 32; off >= 1; off >>= 1) m = fmaxf(m, __shfl_xor(m, off, 64));
    float l = 0.f;
    #pragma unroll
    for (int j = 0; j < 7; ++j) {
        float pv = __builtin_amdgcn_exp2f((sc[j] - m) * LOG2E);  // exp2(-inf)=0
        sc[j] = pv;
        l += pv;
    }
    #pragma unroll
    for (int off = 32; off >= 1; off >>= 1) l += __shfl_xor(l, off, 64);
    float inv = 1.0f / l;
    #pragma unroll
    for (int j = 0; j < 7; ++j) sc[j] *= inv;

    // ---- apply phase: out[q][d] = sum_t p[t]*y[t][d]; lane <-> float4 col ----
    float4 acc = {0.f, 0.f, 0.f, 0.f};
    const int natile = (n + AT - 1) / AT;  // 7..13
    #pragma unroll
    for (int tile = 0; tile < 13; ++tile) {
        if (tile >= natile) break;  // uniform
        __syncthreads();            // prior consumers of s_buf4 done
        #pragma unroll
        for (int k = 0; k < 8; ++k)
            s_buf4[(k * 4 + wave) * 64 + lane] = pf[k];
        if (tile + 1 < natile) {
            const int t0n = (tile + 1) * AT;
            #pragma unroll
            for (int k = 0; k < 8; ++k) {
                int absrow = min(b * TYn + t0n + k * 4 + wave, 8 * TYn - 1);
                pf[k] = yb[(size_t)absrow * 64 + lane];  // overlaps compute below
            }
        }
        __syncthreads();
        const int tmax = min(AT, n - tile * AT);
        const float scj = sc[tile >> 1];  // compile-time index (full unroll)
        for (int ttl = 0; ttl < tmax; ++ttl) {
            float pt = __int_as_float(__builtin_amdgcn_readlane(
                __float_as_int(scj), (tile & 1) * 32 + ttl));
            float4 yv = s_buf4[ttl * 64 + lane];  // contiguous 64-lane sweep
            acc.x = fmaf(pt, yv.x, acc.x);
            acc.y = fmaf(pt, yv.y, acc.y);
            acc.z = fmaf(pt, yv.z, acc.z);
            acc.w = fmaf(pt, yv.w, acc.w);
        }
    }
    float4* op = reinterpret_cast<float4*>(out + (size_t)(b * TQn + q0 + wave) * DD);
    op[lane] = acc;
}

extern "C" void kernel_launch(void* const* d_in, const int* in_sizes, int n_in,
                              void* d_out, int out_size, void* d_ws, size_t ws_size,
                              hipStream_t stream) {
    const float* query = (const float*)d_in[0];
    const float* y     = (const float*)d_in[1];
    const float* Wq_w  = (const float*)d_in[2];
    const float* Wq_b  = (const float*)d_in[3];
    const float* Wy_w  = (const float*)d_in[4];
    const float* Wy_b  = (const float*)d_in[5];
    const float* v_w   = (const float*)d_in[6];
    // d_in[7] = v_b: softmax-invariant, dropped.
    const int* nw      = (const int*)d_in[8];
    float* out = (float*)d_out;

    float* qp = (float*)d_ws;                    // [3200][128]
    float* yp = qp + (size_t)8 * 400 * 128;      // [3200][128]

    proj_kernel<<<800, 128, 0, stream>>>(query, y, Wq_w, Wq_b, Wy_w, Wy_b, qp, yp);
    fused_kernel<<<8 * QBLOCKS, 256, 0, stream>>>(y, qp, yp, v_w, nw, out);
}

// Round 5
// 78.181 us; speedup vs baseline: 1.9807x; 1.9807x over previous
//
#include <hip/hip_runtime.h>

// Bahdanau attention, fused. query [8][400][256], y [8][400][256],
// Wq_w [128][256], Wq_b [128], Wy_w [128][256], Wy_b [128], v_w [1][128],
// v_b (dropped: softmax shift-invariant), n_wins_y [8] i32. out [8][400][256] f32.
// score = sum_a v_a*tanh(qp+yp) ~ sum_a (-2 v_a)/(e^{2x}+1) + const (dropped).
// qp/yp prescaled by 2*log2(e) so exp2(qp'+yp') = e^{2x}. One rcp per 4 elems.
//
// R4: R2/R3's 280MB WRITE_SIZE was scratch traffic from DYNAMIC register-array
// indexing (runtime-bounded loop writing sc[i]; dragged prefetch state to
// scratch too). Fix: constant-trip guarded loops only + named prefetch regs.
// Also QT 4->8 (halves staging traffic; R0 evidence).

#define LOG2E 1.4426950408889634f
#define TANH_SCALE 2.8853900817779268f  // 2*log2(e)

constexpr int TQn = 400, TYn = 400, AD = 128, DD = 256;
constexpr int QT = 8;              // queries per fused block (1 wave each)
constexpr int QBLOCKS = TQn / QT;  // 50
constexpr int YT = 64;             // score tile rows
constexpr int AT = 32;             // apply tile rows
constexpr int SSTR = 65;           // score LDS row stride in float4 (transposed)

// ---------------- projection: qp' = (query@WqT + bq)*S ; yp' likewise ----------
__global__ __launch_bounds__(128, 4) void proj_kernel(
    const float* __restrict__ qin, const float* __restrict__ yin,
    const float* __restrict__ Wq, const float* __restrict__ bq,
    const float* __restrict__ Wy, const float* __restrict__ by,
    float* __restrict__ qp, float* __restrict__ yp)
{
    int blk = blockIdx.x;
    bool is_q = blk < 400;
    int row0 = (is_q ? blk : blk - 400) * 8;
    const float* in   = (is_q ? qin : yin) + (size_t)row0 * DD;
    const float* W    = is_q ? Wq : Wy;
    const float* bias = is_q ? bq : by;
    float* outp = (is_q ? qp : yp) + (size_t)row0 * AD;

    __shared__ float lin[8 * DD];
    {
        const float4* in4 = reinterpret_cast<const float4*>(in);
        float4* l4s = reinterpret_cast<float4*>(lin);
        for (int j = threadIdx.x; j < 8 * DD / 4; j += 128) l4s[j] = in4[j];
    }
    __syncthreads();

    int a = threadIdx.x;  // 0..127
    float acc[8] = {0.f,0.f,0.f,0.f,0.f,0.f,0.f,0.f};
    const float4* w4p = reinterpret_cast<const float4*>(W + (size_t)a * DD);
    const float4* l4 = reinterpret_cast<const float4*>(lin);
    #pragma unroll 4
    for (int d4 = 0; d4 < DD / 4; ++d4) {
        float4 w4 = w4p[d4];
        #pragma unroll
        for (int r = 0; r < 8; ++r) {
            float4 v = l4[r * (DD/4) + d4];  // broadcast
            acc[r] = fmaf(w4.x, v.x, acc[r]);
            acc[r] = fmaf(w4.y, v.y, acc[r]);
            acc[r] = fmaf(w4.z, v.z, acc[r]);
            acc[r] = fmaf(w4.w, v.w, acc[r]);
        }
    }
    float bb = bias[a];
    #pragma unroll
    for (int r = 0; r < 8; ++r)
        outp[(size_t)r * AD + a] = (acc[r] + bb) * TANH_SCALE;
}

// ---------------- fused scores -> masked softmax -> att @ y --------------------
__global__ __launch_bounds__(512, 4) void fused_kernel(
    const float* __restrict__ y,    // [B][TY][DD]
    const float* __restrict__ qp,   // [B*TQ][AD] prescaled
    const float* __restrict__ yp,   // [B*TY][AD] prescaled
    const float* __restrict__ vw,   // [AD]
    const int*  __restrict__ nwins, // [B]
    float* __restrict__ out)        // [B][TQ][DD]
{
    __shared__ float4 s_qp4[QT * 32];       // 4 KB
    __shared__ float4 s_v4[32];             // 0.5 KB (holds -2*v)
    __shared__ float4 s_buf4[32 * SSTR];    // 33.3 KB: yp^T tile / y tile

    const int b  = blockIdx.x / QBLOCKS;
    const int q0 = (blockIdx.x % QBLOCKS) * QT;
    const int tid = threadIdx.x;  // 0..511
    const int wave = tid >> 6;    // local query 0..7
    const int lane = tid & 63;
    const int n = nwins[b];
    const float NEG_INF = -__builtin_inff();

    const float4* ypb = reinterpret_cast<const float4*>(yp);  // rows [3200][32]f4
    const float4* yb  = reinterpret_cast<const float4*>(y);   // rows [3200][64]f4

    // score staging coords: col pcol (a4), rows prow+16k
    const int pcol = tid & 31;
    const int prow = tid >> 5;    // 0..15
    // apply staging coords: col acol (d4), rows arow+8k
    const int acol = tid & 63;
    const int arow = tid >> 6;    // 0..7

    // named prefetch registers (never an indexable array -> cannot hit scratch)
    float4 p0, p1, p2, p3;

    // prefetch score tile 0 (rows 0..63 valid: n >= 200)
    {
        const size_t base = (size_t)(b * TYn) * 32 + pcol;
        p0 = ypb[base + (size_t)(prow +  0) * 32];
        p1 = ypb[base + (size_t)(prow + 16) * 32];
        p2 = ypb[base + (size_t)(prow + 32) * 32];
        p3 = ypb[base + (size_t)(prow + 48) * 32];
    }

    // stage qp tile + (-2*v); visible after first barrier
    if (tid < QT * 32) {
        s_qp4[tid] = reinterpret_cast<const float4*>(qp + (size_t)(b * TQn + q0) * AD)[tid];
    } else if (tid < QT * 32 + 32) {
        float4 v = reinterpret_cast<const float4*>(vw)[tid - QT * 32];
        s_v4[tid - QT * 32] = make_float4(-2.f * v.x, -2.f * v.y, -2.f * v.z, -2.f * v.w);
    }

    float sc[7];
    #pragma unroll
    for (int j = 0; j < 7; ++j) sc[j] = NEG_INF;

    const int ntile = (n + YT - 1) >> 6;  // 4..7, block-uniform

    // ---- score phase: constant-trip loop, uniform guard (no dynamic sc index) ----
    #pragma unroll
    for (int i = 0; i < 7; ++i) {
        if (i < ntile) {
            __syncthreads();  // all waves done reading s_buf4 (covers qp/v on i==0)
            s_buf4[pcol * SSTR + prow +  0] = p0;  // transposed store
            s_buf4[pcol * SSTR + prow + 16] = p1;
            s_buf4[pcol * SSTR + prow + 32] = p2;
            s_buf4[pcol * SSTR + prow + 48] = p3;
            if (i + 1 < ntile) {
                const int t0n = (i + 1) * YT;
                const size_t base = (size_t)(b * TYn) * 32 + pcol;
                int r0 = min(t0n + prow +  0, TYn - 1);
                int r1 = min(t0n + prow + 16, TYn - 1);
                int r2 = min(t0n + prow + 32, TYn - 1);
                int r3 = min(t0n + prow + 48, TYn - 1);
                p0 = ypb[base + (size_t)r0 * 32];  // in flight during compute
                p1 = ypb[base + (size_t)r1 * 32];
                p2 = ypb[base + (size_t)r2 * 32];
                p3 = ypb[base + (size_t)r3 * 32];
            }
            __syncthreads();
            float ac0 = 0.f, ac1 = 0.f, ac2 = 0.f, ac3 = 0.f;
            const float4* qrow = s_qp4 + wave * 32;
            #pragma unroll 8
            for (int a4 = 0; a4 < 32; ++a4) {
                float4 yv = s_buf4[a4 * SSTR + lane];  // contiguous 64-lane sweep
                float4 qv = qrow[a4];                  // wave-uniform broadcast
                float4 vv = s_v4[a4];                  // broadcast (-2v)
                float e0 = __builtin_amdgcn_exp2f(qv.x + yv.x);
                float e1 = __builtin_amdgcn_exp2f(qv.y + yv.y);
                float e2 = __builtin_amdgcn_exp2f(qv.z + yv.z);
                float e3 = __builtin_amdgcn_exp2f(qv.w + yv.w);
                float a0 = e0 + 1.f, a1 = e1 + 1.f, a2 = e2 + 1.f, a3 = e3 + 1.f;
                float p01 = a0 * a1, p23 = a2 * a3;
                float R = __builtin_amdgcn_rcpf(p01 * p23);
                float u = p23 * R, v = p01 * R;        // u=1/p01, v=1/p23
                ac0 = fmaf(vv.x, a1 * u, ac0);
                ac1 = fmaf(vv.y, a0 * u, ac1);
                ac2 = fmaf(vv.z, a3 * v, ac2);
                ac3 = fmaf(vv.w, a2 * v, ac3);
            }
            sc[i] = (ac0 + ac1) + (ac2 + ac3);  // garbage rows masked below
        }
    }

    // prefetch apply tile 0 (rows 0..31 valid: n >= 200); overlaps softmax
    {
        const size_t base = (size_t)(b * TYn) * 64 + acol;
        p0 = yb[base + (size_t)(arow +  0) * 64];
        p1 = yb[base + (size_t)(arow +  8) * 64];
        p2 = yb[base + (size_t)(arow + 16) * 64];
        p3 = yb[base + (size_t)(arow + 24) * 64];
    }

    // ---- mask + softmax over t (full 64-lane wave per q) ----
    #pragma unroll
    for (int j = 0; j < 7; ++j) {
        int t = j * YT + lane;
        if (t >= n) sc[j] = NEG_INF;  // overwrites any garbage/NaN
    }
    float m = sc[0];
    #pragma unroll
    for (int j = 1; j < 7; ++j) m = fmaxf(m, sc[j]);
    #pragma unroll
    for (int off = 32; off >= 1; off >>= 1) m = fmaxf(m, __shfl_xor(m, off, 64));
    float l = 0.f;
    #pragma unroll
    for (int j = 0; j < 7; ++j) {
        float pv = __builtin_amdgcn_exp2f((sc[j] - m) * LOG2E);  // exp2(-inf)=0
        sc[j] = pv;
        l += pv;
    }
    #pragma unroll
    for (int off = 32; off >= 1; off >>= 1) l += __shfl_xor(l, off, 64);
    float inv = 1.0f / l;
    #pragma unroll
    for (int j = 0; j < 7; ++j) sc[j] *= inv;

    // ---- apply phase: out[q][d] = sum_t p[t]*y[t][d]; lane <-> float4 col ----
    float4 acc = {0.f, 0.f, 0.f, 0.f};
    const int natile = (n + AT - 1) / AT;  // 7..13, block-uniform
    #pragma unroll
    for (int tile = 0; tile < 13; ++tile) {
        if (tile < natile) {
            __syncthreads();  // prior consumers of s_buf4 done
            s_buf4[(arow +  0) * 64 + acol] = p0;
            s_buf4[(arow +  8) * 64 + acol] = p1;
            s_buf4[(arow + 16) * 64 + acol] = p2;
            s_buf4[(arow + 24) * 64 + acol] = p3;
            if (tile + 1 < natile) {
                const int t0n = (tile + 1) * AT;
                const size_t base = (size_t)(b * TYn) * 64 + acol;
                int r0 = min(t0n + arow +  0, TYn - 1);
                int r1 = min(t0n + arow +  8, TYn - 1);
                int r2 = min(t0n + arow + 16, TYn - 1);
                int r3 = min(t0n + arow + 24, TYn - 1);
                p0 = yb[base + (size_t)r0 * 64];  // in flight during compute
                p1 = yb[base + (size_t)r1 * 64];
                p2 = yb[base + (size_t)r2 * 64];
                p3 = yb[base + (size_t)r3 * 64];
            }
            __syncthreads();
            const int tmax = min(AT, n - tile * AT);
            const float scj = sc[tile >> 1];  // compile-time index
            for (int ttl = 0; ttl < tmax; ++ttl) {
                float pt = __int_as_float(__builtin_amdgcn_readlane(
                    __float_as_int(scj), (tile & 1) * 32 + ttl));  // uniform lane
                float4 yv = s_buf4[ttl * 64 + lane];  // contiguous 64-lane sweep
                acc.x = fmaf(pt, yv.x, acc.x);
                acc.y = fmaf(pt, yv.y, acc.y);
                acc.z = fmaf(pt, yv.z, acc.z);
                acc.w = fmaf(pt, yv.w, acc.w);
            }
        }
    }
    float4* op = reinterpret_cast<float4*>(out + (size_t)(b * TQn + q0 + wave) * DD);
    op[lane] = acc;
}

extern "C" void kernel_launch(void* const* d_in, const int* in_sizes, int n_in,
                              void* d_out, int out_size, void* d_ws, size_t ws_size,
                              hipStream_t stream) {
    const float* query = (const float*)d_in[0];
    const float* y     = (const float*)d_in[1];
    const float* Wq_w  = (const float*)d_in[2];
    const float* Wq_b  = (const float*)d_in[3];
    const float* Wy_w  = (const float*)d_in[4];
    const float* Wy_b  = (const float*)d_in[5];
    const float* v_w   = (const float*)d_in[6];
    // d_in[7] = v_b: softmax-invariant, dropped.
    const int* nw      = (const int*)d_in[8];
    float* out = (float*)d_out;

    float* qp = (float*)d_ws;                    // [3200][128]
    float* yp = qp + (size_t)8 * 400 * 128;      // [3200][128]

    proj_kernel<<<800, 128, 0, stream>>>(query, y, Wq_w, Wq_b, Wy_w, Wy_b, qp, yp);
    fused_kernel<<<8 * QBLOCKS, 512, 0, stream>>>(y, qp, yp, v_w, nw, out);
}